// Round 20
// baseline (398.935 us; speedup 1.0000x reference)
//
#include <hip/hip_runtime.h>
#include <hip/hip_bf16.h>

#define N_TOK 8192
#define IN_F  2048
#define OUT_F 8192
#define NB    16
#define BS    512
#define BM2   256
#define MAX_MT2 144         // worst-case 256-row M-tiles: 32768/256 + 16

typedef short          bf16x8  __attribute__((ext_vector_type(8)));
typedef unsigned short ushort8 __attribute__((ext_vector_type(8)));
typedef float          f32x4   __attribute__((ext_vector_type(4)));
typedef _Float16       f16x8   __attribute__((ext_vector_type(8)));

// ws layout (peak ~223 MB, identical to R14/R16-green)
#define WS_COUNTS 0
#define WS_TSTART 64
#define WS_SEL    256                           // 8192 u16
#define WS_INV    (32*1024)                     // 8192*4 u32
#define WS_LISTS  (192*1024)                    // 16*8192 int
#define WS_XBF    (1ull<<20)                    // x_bf 32MB swizzled (w2_bf aliases after fc1)
#define WS_W2BF   WS_XBF
#define WS_H      (WS_XBF + 33554432ull)        // h: 36864*512*2 = 36MB
#define WS_W1BF   (WS_H + 37748736ull)          // w1_bf 32MB (dead after fc1)
#define WS_YP     WS_W1BF                       // yp: 36864*2048*2 = 144MB, overlays w1_bf

static __device__ __forceinline__ unsigned short f2bf(float f) {
    __hip_bfloat16 h = __float2bfloat16(f);
    return *reinterpret_cast<unsigned short*>(&h);
}

static __device__ __forceinline__ void gload16(const unsigned short* g, unsigned short* lds) {
    __builtin_amdgcn_global_load_lds(
        (const __attribute__((address_space(1))) unsigned int*)g,
        (__attribute__((address_space(3))) unsigned int*)lds, 16, 0, 0);
}

// ---------------- router: 8 tokens/block, fp64 logits, top-4; emits x_bf (swizzled) ----------------
__global__ __launch_bounds__(512) void router_kernel(
    const float* __restrict__ x, const float* __restrict__ Wr,
    const float* __restrict__ br, unsigned short* __restrict__ sel,
    unsigned short* __restrict__ x_bf)
{
    __shared__ float xs[8][IN_F];
    __shared__ double logits[8][NB];
    const int tid = threadIdx.x;
    const int lt = tid & 63;
    const int wv = tid >> 6;
    const int tok = blockIdx.x * 8 + wv;
    float4* xl = (float4*)xs[wv];
    const float4* xp = (const float4*)(x + (size_t)tok * IN_F);
    #pragma unroll
    for (int i = 0; i < 8; ++i) xl[lt + i * 64] = xp[lt + i * 64];
    __syncthreads();
    const int e = lt >> 2, p = lt & 3;
    const float4* wp = (const float4*)(Wr + (size_t)e * IN_F);
    double s = 0.0;
    for (int j = p; j < IN_F / 4; j += 4) {
        float4 a = xl[j], w = wp[j];
        s += (double)a.x * w.x + (double)a.y * w.y + (double)a.z * w.z + (double)a.w * w.w;
    }
    s += __shfl_down(s, 2);
    s += __shfl_down(s, 1);
    if (p == 0) logits[wv][e] = s + (double)br[e];
    __syncthreads();
    if (lt == 0) {
        unsigned used = 0, packed = 0;
        #pragma unroll
        for (int kk = 0; kk < 4; ++kk) {
            int best = 0; double bv = -1.0e300;
            #pragma unroll
            for (int i = 0; i < NB; ++i)
                if (!((used >> i) & 1u) && logits[wv][i] > bv) { bv = logits[wv][i]; best = i; }
            used |= 1u << best;
            packed |= (unsigned)best << (4 * kk);
        }
        sel[tok] = (unsigned short)packed;
    }
    // emit bf16 row, swizzled: x_bf[tok][slot ^ (tok&7)] = bf16(x[tok][slot])
    const int t7 = tok & 7;
    unsigned short* drow = x_bf + (size_t)tok * IN_F;
    #pragma unroll
    for (int i = 0; i < 4; ++i) {
        const int slot = lt + i * 64;
        const float* sp = &xs[wv][slot * 8];
        ushort8 o;
        #pragma unroll
        for (int j = 0; j < 8; ++j) o[j] = f2bf(sp[j]);
        *(ushort8*)(drow + ((slot ^ t7) << 3)) = o;
    }
}

// ---------------- build per-expert token lists + inverse map (deterministic) ----------------
__global__ __launch_bounds__(256) void build_lists_kernel(
    const unsigned short* __restrict__ sel, int* __restrict__ counts,
    int* __restrict__ lists, unsigned* __restrict__ inv)
{
    const int e = blockIdx.x;
    const int t = threadIdx.x;
    unsigned short mysel[N_TOK / 256];
    int cnt = 0;
    #pragma unroll
    for (int i = 0; i < N_TOK / 256; ++i) {
        unsigned s = sel[i * 256 + t];
        mysel[i] = (unsigned short)s;
        bool m = ((s & 15u) == (unsigned)e) | (((s >> 4) & 15u) == (unsigned)e) |
                 (((s >> 8) & 15u) == (unsigned)e) | (((s >> 12) & 15u) == (unsigned)e);
        cnt += m ? 1 : 0;
    }
    __shared__ int ps[256];
    ps[t] = cnt;
    __syncthreads();
    #pragma unroll
    for (int off = 1; off < 256; off <<= 1) {
        int v = (t >= off) ? ps[t - off] : 0;
        __syncthreads();
        ps[t] += v;
        __syncthreads();
    }
    int pos = ps[t] - cnt;
    if (t == 255) counts[e] = ps[255];
    #pragma unroll
    for (int i = 0; i < N_TOK / 256; ++i) {
        unsigned s = mysel[i];
        bool m = ((s & 15u) == (unsigned)e) | (((s >> 4) & 15u) == (unsigned)e) |
                 (((s >> 8) & 15u) == (unsigned)e) | (((s >> 12) & 15u) == (unsigned)e);
        if (m) {
            const int tok = i * 256 + t;
            int j = ((s & 15u) == (unsigned)e) ? 0 :
                    (((s >> 4) & 15u) == (unsigned)e) ? 1 :
                    (((s >> 8) & 15u) == (unsigned)e) ? 2 : 3;
            inv[tok * 4 + j] = ((unsigned)e << 16) | (unsigned)pos;
            lists[e * N_TOK + pos++] = tok;
        }
    }
}

__global__ void scan_kernel(const int* __restrict__ counts, int* __restrict__ tstart)
{
    if (threadIdx.x == 0) {
        int acc = 0;
        for (int i = 0; i < NB; ++i) { tstart[i] = acc; acc += (counts[i] + BM2 - 1) / BM2; }
        tstart[NB] = acc;
    }
}

// ---------------- W convert: fp32 -> bf16 with per-row XOR-swizzle of 16B k-slots ----------------
__global__ __launch_bounds__(256) void convert_swz_kernel(
    const float* __restrict__ src, unsigned short* __restrict__ dst, int sh)
{
    const int total = 1 << 21;
    for (int id = blockIdx.x * 256 + threadIdx.x; id < total; id += 2048 * 256) {
        const int row = id >> sh;
        const int sr  = id & ((1 << sh) - 1);
        const int ps  = sr ^ (row & 7);
        const float4* s4 = (const float4*)(src + ((size_t)id << 3));
        float4 p0 = s4[0], p1 = s4[1];
        ushort8 o;
        o[0] = f2bf(p0.x); o[1] = f2bf(p0.y); o[2] = f2bf(p0.z); o[3] = f2bf(p0.w);
        o[4] = f2bf(p1.x); o[5] = f2bf(p1.y); o[6] = f2bf(p1.z); o[7] = f2bf(p1.w);
        *(ushort8*)(dst + (((size_t)(row) << sh) << 3) + ((size_t)ps << 3)) = o;
    }
}

// ======== fc1: 256x128 tile, 8 waves, triple-buffer counted-vmcnt(6), ONE 32-MFMA phase per K-step ========
// Identical sync ledger to R14-green (issue 6 loads for k+2, counted vmcnt(6), tail drain);
// the two 16-MFMA half-phases are merged into a single phase (half the barriers/drains).
__global__ __launch_bounds__(512) void fc1_kernel(
    const unsigned short* __restrict__ x_bf, const unsigned short* __restrict__ w1_bf,
    const int* __restrict__ lists, const int* __restrict__ counts,
    const int* __restrict__ tstart, unsigned short* __restrict__ h)
{
    __shared__ unsigned short lds[73728];   // 3 x (A 32KB + B 16KB) = 144KB
    const int bid = blockIdx.x;
    const int newid = (bid & 7) * 72 + (bid >> 3);   // bijective: 576 = 8*72
    const int nt = newid & 3, mt = newid >> 2;
    if (mt >= tstart[NB]) return;
    int b = 0;
    #pragma unroll
    for (int i = 1; i < NB; ++i) b += (mt >= tstart[i]);
    const int cnt  = counts[b];
    const int row0 = (mt - tstart[b]) * BM2;
    const int tid  = threadIdx.x;
    const int wave = tid >> 6, lane = tid & 63;
    const int sph = lane & 7;
    const int rbase = wave * 8 + (lane >> 3);        // 0..63

    const unsigned short* aS[4];
    const unsigned short* bS[2];
    #pragma unroll
    for (int i = 0; i < 4; ++i) {
        const int r = i * 64 + rbase;
        const int gr = min(row0 + r, cnt - 1);
        const int tok = lists[b * N_TOK + gr];
        aS[i] = x_bf + (size_t)tok * IN_F + ((sph ^ (r & 7) ^ (tok & 7)) << 3);
    }
    #pragma unroll
    for (int j = 0; j < 2; ++j) {
        const int r = j * 64 + rbase;
        bS[j] = w1_bf + (size_t)(b * BS + nt * 128 + r) * IN_F + (sph << 3);
    }
    const int wbase = wave * 512;

    const int lr16 = lane & 15, q = lane >> 4;
    const int wm = (wave >> 1) * 64, wn = (wave & 1) * 64;
    int offA[4], offB[4];
    #pragma unroll
    for (int i = 0; i < 4; ++i) { const int r = wm + i * 16 + lr16; offA[i] = r * 64 + ((q ^ (r & 7)) << 3); }
    #pragma unroll
    for (int j = 0; j < 4; ++j) { const int r = wn + j * 16 + lr16; offB[j] = r * 64 + ((q ^ (r & 7)) << 3); }

    f32x4 acc[4][4];
    #pragma unroll
    for (int i = 0; i < 4; ++i)
        #pragma unroll
        for (int j = 0; j < 4; ++j) acc[i][j] = (f32x4)0.0f;

#define STA1(k, buf, i) gload16(aS[i] + (size_t)(k) * 64, lds + (buf) * 24576 + (i) * 4096 + wbase)
#define STB1(k, buf, j) gload16(bS[j] + (size_t)(k) * 64, lds + (buf) * 24576 + 16384 + (j) * 4096 + wbase)

    STA1(0,0,0); STA1(0,0,1); STA1(0,0,2); STA1(0,0,3); STB1(0,0,0); STB1(0,0,1);
    STA1(1,1,0); STA1(1,1,1); STA1(1,1,2); STA1(1,1,3); STB1(1,1,0); STB1(1,1,1);
    asm volatile("s_waitcnt vmcnt(6)" ::: "memory");
    __builtin_amdgcn_s_barrier();

    const int NK = IN_F / 64;   // 32
    int cur = 0;
    for (int k = 0; k < NK; ++k) {
        const unsigned short* Ab = lds + cur * 24576;
        const unsigned short* Bb = Ab + 16384;
        const int nxt = (cur == 0) ? 2 : cur - 1;    // (cur+2)%3
        // read BOTH k-halves of the current tile (16 ds_read_b128 per lane)
        bf16x8 a[8], bb[8];
        #pragma unroll
        for (int i = 0; i < 4; ++i) {
            a[i]      = *(const bf16x8*)&Ab[offA[i]];
            a[4 + i]  = *(const bf16x8*)&Ab[offA[i] ^ 32];
            bb[i]     = *(const bf16x8*)&Bb[offB[i]];
            bb[4 + i] = *(const bf16x8*)&Bb[offB[i] ^ 32];
        }
        // issue all 6 staging loads for tile k+2, then counted wait (k+1's loads landed)
        if (k + 2 < NK) {
            STA1(k + 2, nxt, 0); STA1(k + 2, nxt, 1); STA1(k + 2, nxt, 2); STA1(k + 2, nxt, 3);
            STB1(k + 2, nxt, 0); STB1(k + 2, nxt, 1);
            asm volatile("s_waitcnt vmcnt(6)" ::: "memory");
        } else if (k + 1 < NK) {
            asm volatile("s_waitcnt vmcnt(0)" ::: "memory");
        }
        __builtin_amdgcn_s_barrier();
        asm volatile("s_waitcnt lgkmcnt(0)" ::: "memory");
        __builtin_amdgcn_sched_barrier(0);
        __builtin_amdgcn_s_setprio(1);
        #pragma unroll
        for (int hf = 0; hf < 2; ++hf)
            #pragma unroll
            for (int i = 0; i < 4; ++i)
                #pragma unroll
                for (int j = 0; j < 4; ++j)
                    acc[i][j] = __builtin_amdgcn_mfma_f32_16x16x32_bf16(a[hf * 4 + i], bb[hf * 4 + j], acc[i][j], 0, 0, 0);
        __builtin_amdgcn_s_setprio(0);
        __builtin_amdgcn_sched_barrier(0);
        __builtin_amdgcn_s_barrier();
        cur = (cur == 2) ? 0 : cur + 1;
    }
    // epilogue: exact gelu, store h pre-swizzled by row&7 (16B-slot XOR)
    #pragma unroll
    for (int i = 0; i < 4; ++i) {
        #pragma unroll
        for (int r = 0; r < 4; ++r) {
            const int lrow = wm + i * 16 + q * 4 + r;
            if (row0 + lrow < cnt) {
                const size_t hrow = (size_t)(mt * BM2 + lrow) * BS;
                const int r7 = (lrow & 7) << 3;
                #pragma unroll
                for (int j = 0; j < 4; ++j) {
                    const int col = nt * 128 + wn + j * 16 + lr16;
                    float v = acc[i][j][r];
                    v = 0.5f * v * (1.0f + erff(v * 0.70710678118654752f));
                    h[hrow + (col ^ r7)] = f2bf(v);
                }
            }
        }
    }
#undef STA1
#undef STB1
}

// ======== fc2: 256x256 tile, 8 waves (2x4), 2-buffer phase-interleaved; h @ W2_b^T -> yp fp16 (R12-green) ========
__global__ __launch_bounds__(512) void fc2_kernel(
    const unsigned short* __restrict__ h, const unsigned short* __restrict__ w2_bf,
    const int* __restrict__ counts, const int* __restrict__ tstart,
    _Float16* __restrict__ yp)
{
    __shared__ unsigned short lds[2][32768];   // per buf: A 32KB + B 32KB
    const int bid = blockIdx.x;
    const int newid = (bid & 7) * 144 + (bid >> 3);  // bijective: 1152 = 8*144
    const int nt = newid & 7, mt = newid >> 3;
    if (mt >= tstart[NB]) return;
    int b = 0;
    #pragma unroll
    for (int i = 1; i < NB; ++i) b += (mt >= tstart[i]);
    const int cnt  = counts[b];
    const int row0 = (mt - tstart[b]) * BM2;
    const int tid  = threadIdx.x;
    const int wave = tid >> 6, lane = tid & 63;
    const int sph = lane & 7;
    const int rbase = wave * 8 + (lane >> 3);        // 0..63

    const unsigned short* aS[4];
    const unsigned short* bS[4];
    #pragma unroll
    for (int g = 0; g < 4; ++g) {
        const int r = g * 64 + rbase;
        aS[g] = h + (size_t)(mt * BM2 + r) * BS + (sph << 3);
        bS[g] = w2_bf + (size_t)(nt * 256 + r) * OUT_F + b * BS + (sph << 3);
    }
    const int wbase = wave * 512;

    const int lr16 = lane & 15, q = lane >> 4;
    const int wr = (wave >> 2) * 128, wc = (wave & 3) * 64;
    int offA[8], offB[4];
    #pragma unroll
    for (int i = 0; i < 8; ++i) { const int r = wr + i * 16 + lr16; offA[i] = r * 64 + ((q ^ (r & 7)) << 3); }
    #pragma unroll
    for (int j = 0; j < 4; ++j) { const int r = wc + j * 16 + lr16; offB[j] = 16384 + r * 64 + ((q ^ (r & 7)) << 3); }

    f32x4 acc[8][4];
    #pragma unroll
    for (int i = 0; i < 8; ++i)
        #pragma unroll
        for (int j = 0; j < 4; ++j) acc[i][j] = (f32x4)0.0f;

#define ST2(k, buf) \
    { _Pragma("unroll") for (int g = 0; g < 4; ++g) \
        gload16(aS[g] + (size_t)(k) * 64, &lds[buf][g * 4096 + wbase]); \
      _Pragma("unroll") for (int g = 0; g < 4; ++g) \
        gload16(bS[g] + (size_t)(k) * 64, &lds[buf][16384 + g * 4096 + wbase]); }

#define MFMA_8x4 \
    __builtin_amdgcn_s_barrier(); \
    asm volatile("s_waitcnt lgkmcnt(0)" ::: "memory"); \
    __builtin_amdgcn_sched_barrier(0); \
    __builtin_amdgcn_s_setprio(1); \
    _Pragma("unroll") for (int i = 0; i < 8; ++i) \
        _Pragma("unroll") for (int j = 0; j < 4; ++j) \
            acc[i][j] = __builtin_amdgcn_mfma_f32_16x16x32_bf16(a[i], bb[j], acc[i][j], 0, 0, 0); \
    __builtin_amdgcn_s_setprio(0); \
    __builtin_amdgcn_sched_barrier(0); \
    __builtin_amdgcn_s_barrier();

    ST2(0, 0);
    asm volatile("s_waitcnt vmcnt(0)" ::: "memory");
    __builtin_amdgcn_s_barrier();

    const int NK = BS / 64;   // 8
    for (int k = 0; k < NK; ++k) {
        const int cur = k & 1;
        const unsigned short* L = lds[cur];
        // phase A: ds_read half0, issue ALL of tile k+1's staging
        {
            bf16x8 a[8], bb[4];
            #pragma unroll
            for (int i = 0; i < 8; ++i) a[i]  = *(const bf16x8*)&L[offA[i]];
            #pragma unroll
            for (int j = 0; j < 4; ++j) bb[j] = *(const bf16x8*)&L[offB[j]];
            if (k + 1 < NK) ST2(k + 1, cur ^ 1);
            MFMA_8x4
        }
        // phase B: ds_read half1; drain staging BEFORE the barrier (race-safe)
        {
            bf16x8 a[8], bb[4];
            #pragma unroll
            for (int i = 0; i < 8; ++i) a[i]  = *(const bf16x8*)&L[offA[i] ^ 32];
            #pragma unroll
            for (int j = 0; j < 4; ++j) bb[j] = *(const bf16x8*)&L[offB[j] ^ 32];
            if (k + 1 < NK) asm volatile("s_waitcnt vmcnt(0)" ::: "memory");
            MFMA_8x4
        }
    }
    // epilogue: store fp16 partials
    #pragma unroll
    for (int i = 0; i < 8; ++i) {
        #pragma unroll
        for (int r = 0; r < 4; ++r) {
            const int lrow = wr + i * 16 + q * 4 + r;
            if (row0 + lrow < cnt) {
                _Float16* yrow = yp + (size_t)(mt * BM2 + lrow) * IN_F + nt * 256 + wc + lr16;
                #pragma unroll
                for (int j = 0; j < 4; ++j)
                    yrow[j * 16] = (_Float16)acc[i][j][r];
            }
        }
    }
#undef ST2
#undef MFMA_8x4
}

// ---------------- reduce: y[t] = sum of the token's 4 fp16 partial rows ----------------
__global__ __launch_bounds__(256) void reduce_kernel(
    const _Float16* __restrict__ yp, const unsigned* __restrict__ inv,
    const int* __restrict__ tstart, float* __restrict__ y)
{
    const int tok = blockIdx.x;
    __shared__ size_t rbase[4];
    if (threadIdx.x < 4) {
        unsigned v = inv[tok * 4 + threadIdx.x];
        rbase[threadIdx.x] = (size_t)(tstart[v >> 16] * BM2 + (int)(v & 0xFFFFu)) * IN_F;
    }
    __syncthreads();
    const int c = threadIdx.x * 8;
    f16x8 v0 = *(const f16x8*)(yp + rbase[0] + c);
    f16x8 v1 = *(const f16x8*)(yp + rbase[1] + c);
    f16x8 v2 = *(const f16x8*)(yp + rbase[2] + c);
    f16x8 v3 = *(const f16x8*)(yp + rbase[3] + c);
    float out[8];
    #pragma unroll
    for (int j = 0; j < 8; ++j)
        out[j] = (float)v0[j] + (float)v1[j] + (float)v2[j] + (float)v3[j];
    float4* yo = (float4*)(y + (size_t)tok * IN_F + c);
    yo[0] = make_float4(out[0], out[1], out[2], out[3]);
    yo[1] = make_float4(out[4], out[5], out[6], out[7]);
}

extern "C" void kernel_launch(void* const* d_in, const int* in_sizes, int n_in,
                              void* d_out, int out_size, void* d_ws, size_t ws_size,
                              hipStream_t stream) {
    const float* x  = (const float*)d_in[0];
    const float* Wr = (const float*)d_in[1];
    const float* br = (const float*)d_in[2];
    const float* W1 = (const float*)d_in[3];
    const float* W2 = (const float*)d_in[4];
    float* y = (float*)d_out;
    char* ws = (char*)d_ws;
    int* counts = (int*)(ws + WS_COUNTS);
    int* tstart = (int*)(ws + WS_TSTART);
    unsigned short* sel = (unsigned short*)(ws + WS_SEL);
    unsigned* inv = (unsigned*)(ws + WS_INV);
    int* lists  = (int*)(ws + WS_LISTS);
    unsigned short* x_bf  = (unsigned short*)(ws + WS_XBF);
    unsigned short* w1_bf = (unsigned short*)(ws + WS_W1BF);
    unsigned short* w2_bf = (unsigned short*)(ws + WS_W2BF);
    unsigned short* h     = (unsigned short*)(ws + WS_H);
    _Float16* yp          = (_Float16*)(ws + WS_YP);

    hipLaunchKernelGGL(router_kernel, dim3(N_TOK / 8), dim3(512), 0, stream, x, Wr, br, sel, x_bf);
    hipLaunchKernelGGL(build_lists_kernel, dim3(NB), dim3(256), 0, stream, sel, counts, lists, inv);
    hipLaunchKernelGGL(scan_kernel, dim3(1), dim3(64), 0, stream, counts, tstart);
    hipLaunchKernelGGL(convert_swz_kernel, dim3(2048), dim3(256), 0, stream, W1, w1_bf, 8);
    hipLaunchKernelGGL(fc1_kernel, dim3(4 * MAX_MT2), dim3(512), 0, stream, x_bf, w1_bf, lists, counts, tstart, h);
    hipLaunchKernelGGL(convert_swz_kernel, dim3(2048), dim3(256), 0, stream, W2, w2_bf, 10);
    hipLaunchKernelGGL(fc2_kernel, dim3(8 * MAX_MT2), dim3(512), 0, stream, h, w2_bf, counts, tstart, yp);
    hipLaunchKernelGGL(reduce_kernel, dim3(N_TOK), dim3(256), 0, stream, yp, inv, tstart, y);
}

// Round 21
// 398.547 us; speedup vs baseline: 1.0010x; 1.0010x over previous
//
#include <hip/hip_runtime.h>
#include <hip/hip_bf16.h>

#define N_TOK 8192
#define IN_F  2048
#define OUT_F 8192
#define NB    16
#define BS    512
#define BM2   256
#define MAX_MT2 144         // worst-case 256-row M-tiles: 32768/256 + 16

typedef short          bf16x8  __attribute__((ext_vector_type(8)));
typedef unsigned short ushort8 __attribute__((ext_vector_type(8)));
typedef float          f32x4   __attribute__((ext_vector_type(4)));
typedef _Float16       f16x8   __attribute__((ext_vector_type(8)));

// ws layout (peak ~223 MB, identical to R14/R16-green)
#define WS_COUNTS 0
#define WS_TSTART 64
#define WS_SEL    256                           // 8192 u16
#define WS_INV    (32*1024)                     // 8192*4 u32
#define WS_LISTS  (192*1024)                    // 16*8192 int
#define WS_XBF    (1ull<<20)                    // x_bf 32MB swizzled-by-(tok&3) (w2_bf aliases after fc1)
#define WS_W2BF   WS_XBF
#define WS_H      (WS_XBF + 33554432ull)        // h: 36864*512*2 = 36MB
#define WS_W1BF   (WS_H + 37748736ull)          // w1_bf 32MB swizzled-by-(row&3) (dead after fc1)
#define WS_YP     WS_W1BF                       // yp: 36864*2048*2 = 144MB, overlays w1_bf

static __device__ __forceinline__ unsigned short f2bf(float f) {
    __hip_bfloat16 h = __float2bfloat16(f);
    return *reinterpret_cast<unsigned short*>(&h);
}

static __device__ __forceinline__ void gload16(const unsigned short* g, unsigned short* lds) {
    __builtin_amdgcn_global_load_lds(
        (const __attribute__((address_space(1))) unsigned int*)g,
        (__attribute__((address_space(3))) unsigned int*)lds, 16, 0, 0);
}

// ---------------- router: 8 tokens/block, fp64 logits, top-4; emits x_bf (swizzled by tok&3) ----------------
__global__ __launch_bounds__(512) void router_kernel(
    const float* __restrict__ x, const float* __restrict__ Wr,
    const float* __restrict__ br, unsigned short* __restrict__ sel,
    unsigned short* __restrict__ x_bf)
{
    __shared__ float xs[8][IN_F];
    __shared__ double logits[8][NB];
    const int tid = threadIdx.x;
    const int lt = tid & 63;
    const int wv = tid >> 6;
    const int tok = blockIdx.x * 8 + wv;
    float4* xl = (float4*)xs[wv];
    const float4* xp = (const float4*)(x + (size_t)tok * IN_F);
    #pragma unroll
    for (int i = 0; i < 8; ++i) xl[lt + i * 64] = xp[lt + i * 64];
    __syncthreads();
    const int e = lt >> 2, p = lt & 3;
    const float4* wp = (const float4*)(Wr + (size_t)e * IN_F);
    double s = 0.0;
    for (int j = p; j < IN_F / 4; j += 4) {
        float4 a = xl[j], w = wp[j];
        s += (double)a.x * w.x + (double)a.y * w.y + (double)a.z * w.z + (double)a.w * w.w;
    }
    s += __shfl_down(s, 2);
    s += __shfl_down(s, 1);
    if (p == 0) logits[wv][e] = s + (double)br[e];
    __syncthreads();
    if (lt == 0) {
        unsigned used = 0, packed = 0;
        #pragma unroll
        for (int kk = 0; kk < 4; ++kk) {
            int best = 0; double bv = -1.0e300;
            #pragma unroll
            for (int i = 0; i < NB; ++i)
                if (!((used >> i) & 1u) && logits[wv][i] > bv) { bv = logits[wv][i]; best = i; }
            used |= 1u << best;
            packed |= (unsigned)best << (4 * kk);
        }
        sel[tok] = (unsigned short)packed;
    }
    // emit bf16 row, swizzled: x_bf[tok][slot ^ (tok&3)] = bf16(x[tok][slot])  (within-64B windows)
    const int t3 = tok & 3;
    unsigned short* drow = x_bf + (size_t)tok * IN_F;
    #pragma unroll
    for (int i = 0; i < 4; ++i) {
        const int slot = lt + i * 64;
        const float* sp = &xs[wv][slot * 8];
        ushort8 o;
        #pragma unroll
        for (int j = 0; j < 8; ++j) o[j] = f2bf(sp[j]);
        *(ushort8*)(drow + ((slot ^ t3) << 3)) = o;
    }
}

// ---------------- build per-expert token lists + inverse map (deterministic) ----------------
__global__ __launch_bounds__(256) void build_lists_kernel(
    const unsigned short* __restrict__ sel, int* __restrict__ counts,
    int* __restrict__ lists, unsigned* __restrict__ inv)
{
    const int e = blockIdx.x;
    const int t = threadIdx.x;
    unsigned short mysel[N_TOK / 256];
    int cnt = 0;
    #pragma unroll
    for (int i = 0; i < N_TOK / 256; ++i) {
        unsigned s = sel[i * 256 + t];
        mysel[i] = (unsigned short)s;
        bool m = ((s & 15u) == (unsigned)e) | (((s >> 4) & 15u) == (unsigned)e) |
                 (((s >> 8) & 15u) == (unsigned)e) | (((s >> 12) & 15u) == (unsigned)e);
        cnt += m ? 1 : 0;
    }
    __shared__ int ps[256];
    ps[t] = cnt;
    __syncthreads();
    #pragma unroll
    for (int off = 1; off < 256; off <<= 1) {
        int v = (t >= off) ? ps[t - off] : 0;
        __syncthreads();
        ps[t] += v;
        __syncthreads();
    }
    int pos = ps[t] - cnt;
    if (t == 255) counts[e] = ps[255];
    #pragma unroll
    for (int i = 0; i < N_TOK / 256; ++i) {
        unsigned s = mysel[i];
        bool m = ((s & 15u) == (unsigned)e) | (((s >> 4) & 15u) == (unsigned)e) |
                 (((s >> 8) & 15u) == (unsigned)e) | (((s >> 12) & 15u) == (unsigned)e);
        if (m) {
            const int tok = i * 256 + t;
            int j = ((s & 15u) == (unsigned)e) ? 0 :
                    (((s >> 4) & 15u) == (unsigned)e) ? 1 :
                    (((s >> 8) & 15u) == (unsigned)e) ? 2 : 3;
            inv[tok * 4 + j] = ((unsigned)e << 16) | (unsigned)pos;
            lists[e * N_TOK + pos++] = tok;
        }
    }
}

__global__ void scan_kernel(const int* __restrict__ counts, int* __restrict__ tstart)
{
    if (threadIdx.x == 0) {
        int acc = 0;
        for (int i = 0; i < NB; ++i) { tstart[i] = acc; acc += (counts[i] + BM2 - 1) / BM2; }
        tstart[NB] = acc;
    }
}

// ---------------- W convert: fp32 -> bf16 with per-row XOR-swizzle of 16B k-slots (key = row & mask) ----------------
__global__ __launch_bounds__(256) void convert_swz_kernel(
    const float* __restrict__ src, unsigned short* __restrict__ dst, int sh, int mask)
{
    const int total = 1 << 21;
    for (int id = blockIdx.x * 256 + threadIdx.x; id < total; id += 2048 * 256) {
        const int row = id >> sh;
        const int sr  = id & ((1 << sh) - 1);
        const int ps  = sr ^ (row & mask);
        const float4* s4 = (const float4*)(src + ((size_t)id << 3));
        float4 p0 = s4[0], p1 = s4[1];
        ushort8 o;
        o[0] = f2bf(p0.x); o[1] = f2bf(p0.y); o[2] = f2bf(p0.z); o[3] = f2bf(p0.w);
        o[4] = f2bf(p1.x); o[5] = f2bf(p1.y); o[6] = f2bf(p1.z); o[7] = f2bf(p1.w);
        *(ushort8*)(dst + (((size_t)(row) << sh) << 3) + ((size_t)ps << 3)) = o;
    }
}

// ======== fc1: 256x128 tile, BK=32, 8 waves, 3-buffer (72KB LDS -> 2 blocks/CU), counted vmcnt(3) ========
// R14's exact ledger re-parameterized: issue tile k+2's 3 loads, counted wait, tail drain.
// Swizzle key = (r&3) within 64B windows; W1 store-key == read-key so B staging source is linear.
__global__ __launch_bounds__(512, 4) void fc1_kernel(
    const unsigned short* __restrict__ x_bf, const unsigned short* __restrict__ w1_bf,
    const int* __restrict__ lists, const int* __restrict__ counts,
    const int* __restrict__ tstart, unsigned short* __restrict__ h)
{
    __shared__ unsigned short lds[36864];   // 3 x (A 8192 + B 4096 elems) = 72KB
    const int bid = blockIdx.x;
    const int newid = (bid & 7) * 72 + (bid >> 3);   // bijective: 576 = 8*72
    const int nt = newid & 3, mt = newid >> 2;
    if (mt >= tstart[NB]) return;
    int b = 0;
    #pragma unroll
    for (int i = 1; i < NB; ++i) b += (mt >= tstart[i]);
    const int cnt  = counts[b];
    const int row0 = (mt - tstart[b]) * BM2;
    const int tid  = threadIdx.x;
    const int wave = tid >> 6, lane = tid & 63;
    const int sl = tid & 3;              // staging 16B-slot within 64B window
    const int srw = tid >> 2;            // staging row 0..127

    // A rows srw and srw+128 (gathered); B row srw (linear source: store-key == read-key)
    const unsigned short* aS0;
    const unsigned short* aS1;
    const unsigned short* bS0;
    {
        int gr = min(row0 + srw, cnt - 1);
        int tok = lists[b * N_TOK + gr];
        aS0 = x_bf + (size_t)tok * IN_F + ((sl ^ (srw & 3) ^ (tok & 3)) << 3);
        gr = min(row0 + srw + 128, cnt - 1);
        tok = lists[b * N_TOK + gr];
        aS1 = x_bf + (size_t)tok * IN_F + ((sl ^ ((srw + 128) & 3) ^ (tok & 3)) << 3);
        bS0 = w1_bf + (size_t)(b * BS + nt * 128 + srw) * IN_F + (sl << 3);
    }

    const int lr16 = lane & 15, q = lane >> 4;
    const int wm = (wave >> 1) * 64, wn = (wave & 1) * 64;
    int offA[4], offB[4];
    #pragma unroll
    for (int i = 0; i < 4; ++i) { const int r = wm + i * 16 + lr16; offA[i] = r * 32 + ((q ^ (r & 3)) << 3); }
    #pragma unroll
    for (int j = 0; j < 4; ++j) { const int r = wn + j * 16 + lr16; offB[j] = 8192 + r * 32 + ((q ^ (r & 3)) << 3); }

    f32x4 acc[4][4];
    #pragma unroll
    for (int i = 0; i < 4; ++i)
        #pragma unroll
        for (int j = 0; j < 4; ++j) acc[i][j] = (f32x4)0.0f;

#define ST1(k, buf) \
    { gload16(aS0 + (size_t)(k) * 32, lds + (buf) * 12288 + tid * 8); \
      gload16(aS1 + (size_t)(k) * 32, lds + (buf) * 12288 + 4096 + tid * 8); \
      gload16(bS0 + (size_t)(k) * 32, lds + (buf) * 12288 + 8192 + tid * 8); }

    // prologue: stage tiles 0,1; counted wait (tile 1's 3 loads stay in flight)
    ST1(0, 0); ST1(1, 1);
    asm volatile("s_waitcnt vmcnt(3)" ::: "memory");
    __builtin_amdgcn_s_barrier();

    const int NK = IN_F / 32;   // 64
    int cur = 0;
    for (int k = 0; k < NK; ++k) {
        const unsigned short* L = lds + cur * 12288;
        const int nxt = (cur == 0) ? 2 : cur - 1;        // (cur+2)%3
        bf16x8 a[4], bb[4];
        #pragma unroll
        for (int i = 0; i < 4; ++i) {
            a[i]  = *(const bf16x8*)&L[offA[i]];
            bb[i] = *(const bf16x8*)&L[offB[i]];
        }
        if (k + 2 < NK) {
            ST1(k + 2, nxt);
            asm volatile("s_waitcnt vmcnt(3)" ::: "memory");   // tile k+1 landed; k+2 in flight
        } else if (k + 1 < NK) {
            asm volatile("s_waitcnt vmcnt(0)" ::: "memory");   // tail drain
        }
        __builtin_amdgcn_s_barrier();
        asm volatile("s_waitcnt lgkmcnt(0)" ::: "memory");
        __builtin_amdgcn_sched_barrier(0);
        __builtin_amdgcn_s_setprio(1);
        #pragma unroll
        for (int i = 0; i < 4; ++i)
            #pragma unroll
            for (int j = 0; j < 4; ++j)
                acc[i][j] = __builtin_amdgcn_mfma_f32_16x16x32_bf16(a[i], bb[j], acc[i][j], 0, 0, 0);
        __builtin_amdgcn_s_setprio(0);
        __builtin_amdgcn_sched_barrier(0);
        __builtin_amdgcn_s_barrier();
        cur = (cur == 2) ? 0 : cur + 1;
    }
    // epilogue: exact gelu, store h pre-swizzled by row&7 (fc2's expected layout, unchanged)
    #pragma unroll
    for (int i = 0; i < 4; ++i) {
        #pragma unroll
        for (int r = 0; r < 4; ++r) {
            const int lrow = wm + i * 16 + q * 4 + r;
            if (row0 + lrow < cnt) {
                const size_t hrow = (size_t)(mt * BM2 + lrow) * BS;
                const int r7 = (lrow & 7) << 3;
                #pragma unroll
                for (int j = 0; j < 4; ++j) {
                    const int col = nt * 128 + wn + j * 16 + lr16;
                    float v = acc[i][j][r];
                    v = 0.5f * v * (1.0f + erff(v * 0.70710678118654752f));
                    h[hrow + (col ^ r7)] = f2bf(v);
                }
            }
        }
    }
#undef ST1
}

// ======== fc2: 256x256 tile, 8 waves (2x4), 2-buffer phase-interleaved; h @ W2_b^T -> yp fp16 (R12-green) ========
__global__ __launch_bounds__(512) void fc2_kernel(
    const unsigned short* __restrict__ h, const unsigned short* __restrict__ w2_bf,
    const int* __restrict__ counts, const int* __restrict__ tstart,
    _Float16* __restrict__ yp)
{
    __shared__ unsigned short lds[2][32768];   // per buf: A 32KB + B 32KB
    const int bid = blockIdx.x;
    const int newid = (bid & 7) * 144 + (bid >> 3);  // bijective: 1152 = 8*144
    const int nt = newid & 7, mt = newid >> 3;
    if (mt >= tstart[NB]) return;
    int b = 0;
    #pragma unroll
    for (int i = 1; i < NB; ++i) b += (mt >= tstart[i]);
    const int cnt  = counts[b];
    const int row0 = (mt - tstart[b]) * BM2;
    const int tid  = threadIdx.x;
    const int wave = tid >> 6, lane = tid & 63;
    const int sph = lane & 7;
    const int rbase = wave * 8 + (lane >> 3);        // 0..63

    const unsigned short* aS[4];
    const unsigned short* bS[4];
    #pragma unroll
    for (int g = 0; g < 4; ++g) {
        const int r = g * 64 + rbase;
        aS[g] = h + (size_t)(mt * BM2 + r) * BS + (sph << 3);
        bS[g] = w2_bf + (size_t)(nt * 256 + r) * OUT_F + b * BS + (sph << 3);
    }
    const int wbase = wave * 512;

    const int lr16 = lane & 15, q = lane >> 4;
    const int wr = (wave >> 2) * 128, wc = (wave & 3) * 64;
    int offA[8], offB[4];
    #pragma unroll
    for (int i = 0; i < 8; ++i) { const int r = wr + i * 16 + lr16; offA[i] = r * 64 + ((q ^ (r & 7)) << 3); }
    #pragma unroll
    for (int j = 0; j < 4; ++j) { const int r = wc + j * 16 + lr16; offB[j] = 16384 + r * 64 + ((q ^ (r & 7)) << 3); }

    f32x4 acc[8][4];
    #pragma unroll
    for (int i = 0; i < 8; ++i)
        #pragma unroll
        for (int j = 0; j < 4; ++j) acc[i][j] = (f32x4)0.0f;

#define ST2(k, buf) \
    { _Pragma("unroll") for (int g = 0; g < 4; ++g) \
        gload16(aS[g] + (size_t)(k) * 64, &lds[buf][g * 4096 + wbase]); \
      _Pragma("unroll") for (int g = 0; g < 4; ++g) \
        gload16(bS[g] + (size_t)(k) * 64, &lds[buf][16384 + g * 4096 + wbase]); }

#define MFMA_8x4 \
    __builtin_amdgcn_s_barrier(); \
    asm volatile("s_waitcnt lgkmcnt(0)" ::: "memory"); \
    __builtin_amdgcn_sched_barrier(0); \
    __builtin_amdgcn_s_setprio(1); \
    _Pragma("unroll") for (int i = 0; i < 8; ++i) \
        _Pragma("unroll") for (int j = 0; j < 4; ++j) \
            acc[i][j] = __builtin_amdgcn_mfma_f32_16x16x32_bf16(a[i], bb[j], acc[i][j], 0, 0, 0); \
    __builtin_amdgcn_s_setprio(0); \
    __builtin_amdgcn_sched_barrier(0); \
    __builtin_amdgcn_s_barrier();

    ST2(0, 0);
    asm volatile("s_waitcnt vmcnt(0)" ::: "memory");
    __builtin_amdgcn_s_barrier();

    const int NK = BS / 64;   // 8
    for (int k = 0; k < NK; ++k) {
        const int cur = k & 1;
        const unsigned short* L = lds[cur];
        // phase A: ds_read half0, issue ALL of tile k+1's staging
        {
            bf16x8 a[8], bb[4];
            #pragma unroll
            for (int i = 0; i < 8; ++i) a[i]  = *(const bf16x8*)&L[offA[i]];
            #pragma unroll
            for (int j = 0; j < 4; ++j) bb[j] = *(const bf16x8*)&L[offB[j]];
            if (k + 1 < NK) ST2(k + 1, cur ^ 1);
            MFMA_8x4
        }
        // phase B: ds_read half1; drain staging BEFORE the barrier (race-safe)
        {
            bf16x8 a[8], bb[4];
            #pragma unroll
            for (int i = 0; i < 8; ++i) a[i]  = *(const bf16x8*)&L[offA[i] ^ 32];
            #pragma unroll
            for (int j = 0; j < 4; ++j) bb[j] = *(const bf16x8*)&L[offB[j] ^ 32];
            if (k + 1 < NK) asm volatile("s_waitcnt vmcnt(0)" ::: "memory");
            MFMA_8x4
        }
    }
    // epilogue: store fp16 partials
    #pragma unroll
    for (int i = 0; i < 8; ++i) {
        #pragma unroll
        for (int r = 0; r < 4; ++r) {
            const int lrow = wr + i * 16 + q * 4 + r;
            if (row0 + lrow < cnt) {
                _Float16* yrow = yp + (size_t)(mt * BM2 + lrow) * IN_F + nt * 256 + wc + lr16;
                #pragma unroll
                for (int j = 0; j < 4; ++j)
                    yrow[j * 16] = (_Float16)acc[i][j][r];
            }
        }
    }
#undef ST2
#undef MFMA_8x4
}

// ---------------- reduce: y[t] = sum of the token's 4 fp16 partial rows ----------------
__global__ __launch_bounds__(256) void reduce_kernel(
    const _Float16* __restrict__ yp, const unsigned* __restrict__ inv,
    const int* __restrict__ tstart, float* __restrict__ y)
{
    const int tok = blockIdx.x;
    __shared__ size_t rbase[4];
    if (threadIdx.x < 4) {
        unsigned v = inv[tok * 4 + threadIdx.x];
        rbase[threadIdx.x] = (size_t)(tstart[v >> 16] * BM2 + (int)(v & 0xFFFFu)) * IN_F;
    }
    __syncthreads();
    const int c = threadIdx.x * 8;
    f16x8 v0 = *(const f16x8*)(yp + rbase[0] + c);
    f16x8 v1 = *(const f16x8*)(yp + rbase[1] + c);
    f16x8 v2 = *(const f16x8*)(yp + rbase[2] + c);
    f16x8 v3 = *(const f16x8*)(yp + rbase[3] + c);
    float out[8];
    #pragma unroll
    for (int j = 0; j < 8; ++j)
        out[j] = (float)v0[j] + (float)v1[j] + (float)v2[j] + (float)v3[j];
    float4* yo = (float4*)(y + (size_t)tok * IN_F + c);
    yo[0] = make_float4(out[0], out[1], out[2], out[3]);
    yo[1] = make_float4(out[4], out[5], out[6], out[7]);
}

extern "C" void kernel_launch(void* const* d_in, const int* in_sizes, int n_in,
                              void* d_out, int out_size, void* d_ws, size_t ws_size,
                              hipStream_t stream) {
    const float* x  = (const float*)d_in[0];
    const float* Wr = (const float*)d_in[1];
    const float* br = (const float*)d_in[2];
    const float* W1 = (const float*)d_in[3];
    const float* W2 = (const float*)d_in[4];
    float* y = (float*)d_out;
    char* ws = (char*)d_ws;
    int* counts = (int*)(ws + WS_COUNTS);
    int* tstart = (int*)(ws + WS_TSTART);
    unsigned short* sel = (unsigned short*)(ws + WS_SEL);
    unsigned* inv = (unsigned*)(ws + WS_INV);
    int* lists  = (int*)(ws + WS_LISTS);
    unsigned short* x_bf  = (unsigned short*)(ws + WS_XBF);
    unsigned short* w1_bf = (unsigned short*)(ws + WS_W1BF);
    unsigned short* w2_bf = (unsigned short*)(ws + WS_W2BF);
    unsigned short* h     = (unsigned short*)(ws + WS_H);
    _Float16* yp          = (_Float16*)(ws + WS_YP);

    hipLaunchKernelGGL(router_kernel, dim3(N_TOK / 8), dim3(512), 0, stream, x, Wr, br, sel, x_bf);
    hipLaunchKernelGGL(build_lists_kernel, dim3(NB), dim3(256), 0, stream, sel, counts, lists, inv);
    hipLaunchKernelGGL(scan_kernel, dim3(1), dim3(64), 0, stream, counts, tstart);
    hipLaunchKernelGGL(convert_swz_kernel, dim3(2048), dim3(256), 0, stream, W1, w1_bf, 8, 3);
    hipLaunchKernelGGL(fc1_kernel, dim3(4 * MAX_MT2), dim3(512), 0, stream, x_bf, w1_bf, lists, counts, tstart, h);
    hipLaunchKernelGGL(convert_swz_kernel, dim3(2048), dim3(256), 0, stream, W2, w2_bf, 10, 7);
    hipLaunchKernelGGL(fc2_kernel, dim3(8 * MAX_MT2), dim3(512), 0, stream, h, w2_bf, counts, tstart, yp);
    hipLaunchKernelGGL(reduce_kernel, dim3(N_TOK), dim3(256), 0, stream, yp, inv, tstart, y);
}

// Round 22
// 392.713 us; speedup vs baseline: 1.0158x; 1.0149x over previous
//
#include <hip/hip_runtime.h>
#include <hip/hip_bf16.h>

#define N_TOK 8192
#define IN_F  2048
#define OUT_F 8192
#define NB    16
#define BS    512
#define BM2   256
#define MAX_MT2 144         // worst-case 256-row M-tiles: 32768/256 + 16

typedef short          bf16x8  __attribute__((ext_vector_type(8)));
typedef unsigned short ushort8 __attribute__((ext_vector_type(8)));
typedef float          f32x4   __attribute__((ext_vector_type(4)));
typedef _Float16       f16x8   __attribute__((ext_vector_type(8)));

// ws layout (peak ~223 MB)
#define WS_COUNTS 0
#define WS_TSTART 64
#define WS_SEL    256                           // 8192 u16
#define WS_INV    (32*1024)                     // 8192*4 u32
#define WS_LISTS  (192*1024)                    // 16*8192 int
#define WS_XBF    (1ull<<20)                    // x_bf 32MB swizzled-by-(tok&3) (w2_bf aliases after fc1)
#define WS_W2BF   WS_XBF
#define WS_H      (WS_XBF + 33554432ull)        // h: 36864*512*2 = 36MB
#define WS_W1BF   (WS_H + 37748736ull)          // w1_bf 32MB swizzled-by-((row>>1)&3) (dead after fc1)
#define WS_YP     WS_W1BF                       // yp: 36864*2048*2 = 144MB, overlays w1_bf

static __device__ __forceinline__ unsigned short f2bf(float f) {
    __hip_bfloat16 h = __float2bfloat16(f);
    return *reinterpret_cast<unsigned short*>(&h);
}

static __device__ __forceinline__ void gload16(const unsigned short* g, unsigned short* lds) {
    __builtin_amdgcn_global_load_lds(
        (const __attribute__((address_space(1))) unsigned int*)g,
        (__attribute__((address_space(3))) unsigned int*)lds, 16, 0, 0);
}

// ---------------- router: 8 tokens/block, fp64 logits, top-4; emits x_bf (swizzled by tok&3) ----------------
__global__ __launch_bounds__(512) void router_kernel(
    const float* __restrict__ x, const float* __restrict__ Wr,
    const float* __restrict__ br, unsigned short* __restrict__ sel,
    unsigned short* __restrict__ x_bf)
{
    __shared__ float xs[8][IN_F];
    __shared__ double logits[8][NB];
    const int tid = threadIdx.x;
    const int lt = tid & 63;
    const int wv = tid >> 6;
    const int tok = blockIdx.x * 8 + wv;
    float4* xl = (float4*)xs[wv];
    const float4* xp = (const float4*)(x + (size_t)tok * IN_F);
    #pragma unroll
    for (int i = 0; i < 8; ++i) xl[lt + i * 64] = xp[lt + i * 64];
    __syncthreads();
    const int e = lt >> 2, p = lt & 3;
    const float4* wp = (const float4*)(Wr + (size_t)e * IN_F);
    double s = 0.0;
    for (int j = p; j < IN_F / 4; j += 4) {
        float4 a = xl[j], w = wp[j];
        s += (double)a.x * w.x + (double)a.y * w.y + (double)a.z * w.z + (double)a.w * w.w;
    }
    s += __shfl_down(s, 2);
    s += __shfl_down(s, 1);
    if (p == 0) logits[wv][e] = s + (double)br[e];
    __syncthreads();
    if (lt == 0) {
        unsigned used = 0, packed = 0;
        #pragma unroll
        for (int kk = 0; kk < 4; ++kk) {
            int best = 0; double bv = -1.0e300;
            #pragma unroll
            for (int i = 0; i < NB; ++i)
                if (!((used >> i) & 1u) && logits[wv][i] > bv) { bv = logits[wv][i]; best = i; }
            used |= 1u << best;
            packed |= (unsigned)best << (4 * kk);
        }
        sel[tok] = (unsigned short)packed;
    }
    // emit bf16 row, swizzled: x_bf[tok][slot ^ (tok&3)] = bf16(x[tok][slot])  (within-64B windows)
    const int t3 = tok & 3;
    unsigned short* drow = x_bf + (size_t)tok * IN_F;
    #pragma unroll
    for (int i = 0; i < 4; ++i) {
        const int slot = lt + i * 64;
        const float* sp = &xs[wv][slot * 8];
        ushort8 o;
        #pragma unroll
        for (int j = 0; j < 8; ++j) o[j] = f2bf(sp[j]);
        *(ushort8*)(drow + ((slot ^ t3) << 3)) = o;
    }
}

// ---------------- build per-expert token lists + inverse map (deterministic) ----------------
__global__ __launch_bounds__(256) void build_lists_kernel(
    const unsigned short* __restrict__ sel, int* __restrict__ counts,
    int* __restrict__ lists, unsigned* __restrict__ inv)
{
    const int e = blockIdx.x;
    const int t = threadIdx.x;
    unsigned short mysel[N_TOK / 256];
    int cnt = 0;
    #pragma unroll
    for (int i = 0; i < N_TOK / 256; ++i) {
        unsigned s = sel[i * 256 + t];
        mysel[i] = (unsigned short)s;
        bool m = ((s & 15u) == (unsigned)e) | (((s >> 4) & 15u) == (unsigned)e) |
                 (((s >> 8) & 15u) == (unsigned)e) | (((s >> 12) & 15u) == (unsigned)e);
        cnt += m ? 1 : 0;
    }
    __shared__ int ps[256];
    ps[t] = cnt;
    __syncthreads();
    #pragma unroll
    for (int off = 1; off < 256; off <<= 1) {
        int v = (t >= off) ? ps[t - off] : 0;
        __syncthreads();
        ps[t] += v;
        __syncthreads();
    }
    int pos = ps[t] - cnt;
    if (t == 255) counts[e] = ps[255];
    #pragma unroll
    for (int i = 0; i < N_TOK / 256; ++i) {
        unsigned s = mysel[i];
        bool m = ((s & 15u) == (unsigned)e) | (((s >> 4) & 15u) == (unsigned)e) |
                 (((s >> 8) & 15u) == (unsigned)e) | (((s >> 12) & 15u) == (unsigned)e);
        if (m) {
            const int tok = i * 256 + t;
            int j = ((s & 15u) == (unsigned)e) ? 0 :
                    (((s >> 4) & 15u) == (unsigned)e) ? 1 :
                    (((s >> 8) & 15u) == (unsigned)e) ? 2 : 3;
            inv[tok * 4 + j] = ((unsigned)e << 16) | (unsigned)pos;
            lists[e * N_TOK + pos++] = tok;
        }
    }
}

__global__ void scan_kernel(const int* __restrict__ counts, int* __restrict__ tstart)
{
    if (threadIdx.x == 0) {
        int acc = 0;
        for (int i = 0; i < NB; ++i) { tstart[i] = acc; acc += (counts[i] + BM2 - 1) / BM2; }
        tstart[NB] = acc;
    }
}

// ---------------- W convert: fp32 -> bf16, slot-XOR key = (row >> rsh) & mask ----------------
__global__ __launch_bounds__(256) void convert_swz_kernel(
    const float* __restrict__ src, unsigned short* __restrict__ dst, int sh, int rsh, int mask)
{
    const int total = 1 << 21;
    for (int id = blockIdx.x * 256 + threadIdx.x; id < total; id += 2048 * 256) {
        const int row = id >> sh;
        const int sr  = id & ((1 << sh) - 1);
        const int ps  = sr ^ ((row >> rsh) & mask);
        const float4* s4 = (const float4*)(src + ((size_t)id << 3));
        float4 p0 = s4[0], p1 = s4[1];
        ushort8 o;
        o[0] = f2bf(p0.x); o[1] = f2bf(p0.y); o[2] = f2bf(p0.z); o[3] = f2bf(p0.w);
        o[4] = f2bf(p1.x); o[5] = f2bf(p1.y); o[6] = f2bf(p1.z); o[7] = f2bf(p1.w);
        *(ushort8*)(dst + (((size_t)(row) << sh) << 3) + ((size_t)ps << 3)) = o;
    }
}

// ======== fc1: 256x128 tile, BK=32, 8 waves, 3-buffer (72KB LDS -> 2 blocks/CU), counted vmcnt(3) ========
// Swizzle key = ((r>>1)&3): 8 distinct banks x 2 lanes per 16-lane group -> conflict-free (R17-verified family).
__global__ __launch_bounds__(512, 4) void fc1_kernel(
    const unsigned short* __restrict__ x_bf, const unsigned short* __restrict__ w1_bf,
    const int* __restrict__ lists, const int* __restrict__ counts,
    const int* __restrict__ tstart, unsigned short* __restrict__ h)
{
    __shared__ unsigned short lds[36864];   // 3 x (A 8192 + B 4096 elems) = 72KB
    const int bid = blockIdx.x;
    const int newid = (bid & 7) * 72 + (bid >> 3);   // bijective: 576 = 8*72
    const int nt = newid & 3, mt = newid >> 2;
    if (mt >= tstart[NB]) return;
    int b = 0;
    #pragma unroll
    for (int i = 1; i < NB; ++i) b += (mt >= tstart[i]);
    const int cnt  = counts[b];
    const int row0 = (mt - tstart[b]) * BM2;
    const int tid  = threadIdx.x;
    const int wave = tid >> 6, lane = tid & 63;
    const int sl = tid & 3;              // staging 16B-slot within 64B window
    const int srw = tid >> 2;            // staging row 0..127
    const int skey = (srw >> 1) & 3;     // same key for srw and srw+128 ((+128)>>1 adds 64 ≡ 0 mod 4)

    const unsigned short* aS0;
    const unsigned short* aS1;
    const unsigned short* bS0;
    {
        int gr = min(row0 + srw, cnt - 1);
        int tok = lists[b * N_TOK + gr];
        aS0 = x_bf + (size_t)tok * IN_F + ((sl ^ skey ^ (tok & 3)) << 3);
        gr = min(row0 + srw + 128, cnt - 1);
        tok = lists[b * N_TOK + gr];
        aS1 = x_bf + (size_t)tok * IN_F + ((sl ^ skey ^ (tok & 3)) << 3);
        bS0 = w1_bf + (size_t)(b * BS + nt * 128 + srw) * IN_F + (sl << 3);   // store-key == read-key -> linear
    }

    const int lr16 = lane & 15, q = lane >> 4;
    const int wm = (wave >> 1) * 64, wn = (wave & 1) * 64;
    int offA[4], offB[4];
    #pragma unroll
    for (int i = 0; i < 4; ++i) { const int r = wm + i * 16 + lr16; offA[i] = r * 32 + ((q ^ ((r >> 1) & 3)) << 3); }
    #pragma unroll
    for (int j = 0; j < 4; ++j) { const int r = wn + j * 16 + lr16; offB[j] = 8192 + r * 32 + ((q ^ ((r >> 1) & 3)) << 3); }

    f32x4 acc[4][4];
    #pragma unroll
    for (int i = 0; i < 4; ++i)
        #pragma unroll
        for (int j = 0; j < 4; ++j) acc[i][j] = (f32x4)0.0f;

#define ST1(k, buf) \
    { gload16(aS0 + (size_t)(k) * 32, lds + (buf) * 12288 + tid * 8); \
      gload16(aS1 + (size_t)(k) * 32, lds + (buf) * 12288 + 4096 + tid * 8); \
      gload16(bS0 + (size_t)(k) * 32, lds + (buf) * 12288 + 8192 + tid * 8); }

    ST1(0, 0); ST1(1, 1);
    asm volatile("s_waitcnt vmcnt(3)" ::: "memory");
    __builtin_amdgcn_s_barrier();

    const int NK = IN_F / 32;   // 64
    int cur = 0;
    for (int k = 0; k < NK; ++k) {
        const unsigned short* L = lds + cur * 12288;
        const int nxt = (cur == 0) ? 2 : cur - 1;        // (cur+2)%3
        bf16x8 a[4], bb[4];
        #pragma unroll
        for (int i = 0; i < 4; ++i) {
            a[i]  = *(const bf16x8*)&L[offA[i]];
            bb[i] = *(const bf16x8*)&L[offB[i]];
        }
        if (k + 2 < NK) {
            ST1(k + 2, nxt);
            asm volatile("s_waitcnt vmcnt(3)" ::: "memory");   // tile k+1 landed; k+2 in flight
        } else if (k + 1 < NK) {
            asm volatile("s_waitcnt vmcnt(0)" ::: "memory");   // tail drain
        }
        __builtin_amdgcn_s_barrier();
        asm volatile("s_waitcnt lgkmcnt(0)" ::: "memory");
        __builtin_amdgcn_sched_barrier(0);
        __builtin_amdgcn_s_setprio(1);
        #pragma unroll
        for (int i = 0; i < 4; ++i)
            #pragma unroll
            for (int j = 0; j < 4; ++j)
                acc[i][j] = __builtin_amdgcn_mfma_f32_16x16x32_bf16(a[i], bb[j], acc[i][j], 0, 0, 0);
        __builtin_amdgcn_s_setprio(0);
        __builtin_amdgcn_sched_barrier(0);
        __builtin_amdgcn_s_barrier();
        cur = (cur == 2) ? 0 : cur + 1;
    }
    // epilogue: exact gelu, store h pre-swizzled by row&7 (fc2's expected layout, unchanged)
    #pragma unroll
    for (int i = 0; i < 4; ++i) {
        #pragma unroll
        for (int r = 0; r < 4; ++r) {
            const int lrow = wm + i * 16 + q * 4 + r;
            if (row0 + lrow < cnt) {
                const size_t hrow = (size_t)(mt * BM2 + lrow) * BS;
                const int r7 = (lrow & 7) << 3;
                #pragma unroll
                for (int j = 0; j < 4; ++j) {
                    const int col = nt * 128 + wn + j * 16 + lr16;
                    float v = acc[i][j][r];
                    v = 0.5f * v * (1.0f + erff(v * 0.70710678118654752f));
                    h[hrow + (col ^ r7)] = f2bf(v);
                }
            }
        }
    }
#undef ST1
}

// ======== fc2: 256x256 tile, 8 waves (2x4), 2-buffer phase-interleaved; h @ W2_b^T -> yp fp16 (R12-green) ========
__global__ __launch_bounds__(512) void fc2_kernel(
    const unsigned short* __restrict__ h, const unsigned short* __restrict__ w2_bf,
    const int* __restrict__ counts, const int* __restrict__ tstart,
    _Float16* __restrict__ yp)
{
    __shared__ unsigned short lds[2][32768];   // per buf: A 32KB + B 32KB
    const int bid = blockIdx.x;
    const int newid = (bid & 7) * 144 + (bid >> 3);  // bijective: 1152 = 8*144
    const int nt = newid & 7, mt = newid >> 3;
    if (mt >= tstart[NB]) return;
    int b = 0;
    #pragma unroll
    for (int i = 1; i < NB; ++i) b += (mt >= tstart[i]);
    const int cnt  = counts[b];
    const int row0 = (mt - tstart[b]) * BM2;
    const int tid  = threadIdx.x;
    const int wave = tid >> 6, lane = tid & 63;
    const int sph = lane & 7;
    const int rbase = wave * 8 + (lane >> 3);        // 0..63

    const unsigned short* aS[4];
    const unsigned short* bS[4];
    #pragma unroll
    for (int g = 0; g < 4; ++g) {
        const int r = g * 64 + rbase;
        aS[g] = h + (size_t)(mt * BM2 + r) * BS + (sph << 3);
        bS[g] = w2_bf + (size_t)(nt * 256 + r) * OUT_F + b * BS + (sph << 3);
    }
    const int wbase = wave * 512;

    const int lr16 = lane & 15, q = lane >> 4;
    const int wr = (wave >> 2) * 128, wc = (wave & 3) * 64;
    int offA[8], offB[4];
    #pragma unroll
    for (int i = 0; i < 8; ++i) { const int r = wr + i * 16 + lr16; offA[i] = r * 64 + ((q ^ (r & 7)) << 3); }
    #pragma unroll
    for (int j = 0; j < 4; ++j) { const int r = wc + j * 16 + lr16; offB[j] = 16384 + r * 64 + ((q ^ (r & 7)) << 3); }

    f32x4 acc[8][4];
    #pragma unroll
    for (int i = 0; i < 8; ++i)
        #pragma unroll
        for (int j = 0; j < 4; ++j) acc[i][j] = (f32x4)0.0f;

#define ST2(k, buf) \
    { _Pragma("unroll") for (int g = 0; g < 4; ++g) \
        gload16(aS[g] + (size_t)(k) * 64, &lds[buf][g * 4096 + wbase]); \
      _Pragma("unroll") for (int g = 0; g < 4; ++g) \
        gload16(bS[g] + (size_t)(k) * 64, &lds[buf][16384 + g * 4096 + wbase]); }

#define MFMA_8x4 \
    __builtin_amdgcn_s_barrier(); \
    asm volatile("s_waitcnt lgkmcnt(0)" ::: "memory"); \
    __builtin_amdgcn_sched_barrier(0); \
    __builtin_amdgcn_s_setprio(1); \
    _Pragma("unroll") for (int i = 0; i < 8; ++i) \
        _Pragma("unroll") for (int j = 0; j < 4; ++j) \
            acc[i][j] = __builtin_amdgcn_mfma_f32_16x16x32_bf16(a[i], bb[j], acc[i][j], 0, 0, 0); \
    __builtin_amdgcn_s_setprio(0); \
    __builtin_amdgcn_sched_barrier(0); \
    __builtin_amdgcn_s_barrier();

    ST2(0, 0);
    asm volatile("s_waitcnt vmcnt(0)" ::: "memory");
    __builtin_amdgcn_s_barrier();

    const int NK = BS / 64;   // 8
    for (int k = 0; k < NK; ++k) {
        const int cur = k & 1;
        const unsigned short* L = lds[cur];
        // phase A: ds_read half0, issue ALL of tile k+1's staging
        {
            bf16x8 a[8], bb[4];
            #pragma unroll
            for (int i = 0; i < 8; ++i) a[i]  = *(const bf16x8*)&L[offA[i]];
            #pragma unroll
            for (int j = 0; j < 4; ++j) bb[j] = *(const bf16x8*)&L[offB[j]];
            if (k + 1 < NK) ST2(k + 1, cur ^ 1);
            MFMA_8x4
        }
        // phase B: ds_read half1; drain staging BEFORE the barrier (race-safe)
        {
            bf16x8 a[8], bb[4];
            #pragma unroll
            for (int i = 0; i < 8; ++i) a[i]  = *(const bf16x8*)&L[offA[i] ^ 32];
            #pragma unroll
            for (int j = 0; j < 4; ++j) bb[j] = *(const bf16x8*)&L[offB[j] ^ 32];
            if (k + 1 < NK) asm volatile("s_waitcnt vmcnt(0)" ::: "memory");
            MFMA_8x4
        }
    }
    // epilogue: store fp16 partials
    #pragma unroll
    for (int i = 0; i < 8; ++i) {
        #pragma unroll
        for (int r = 0; r < 4; ++r) {
            const int lrow = wr + i * 16 + q * 4 + r;
            if (row0 + lrow < cnt) {
                _Float16* yrow = yp + (size_t)(mt * BM2 + lrow) * IN_F + nt * 256 + wc + lr16;
                #pragma unroll
                for (int j = 0; j < 4; ++j)
                    yrow[j * 16] = (_Float16)acc[i][j][r];
            }
        }
    }
#undef ST2
#undef MFMA_8x4
}

// ---------------- reduce: y[t] = sum of the token's 4 fp16 partial rows ----------------
__global__ __launch_bounds__(256) void reduce_kernel(
    const _Float16* __restrict__ yp, const unsigned* __restrict__ inv,
    const int* __restrict__ tstart, float* __restrict__ y)
{
    const int tok = blockIdx.x;
    __shared__ size_t rbase[4];
    if (threadIdx.x < 4) {
        unsigned v = inv[tok * 4 + threadIdx.x];
        rbase[threadIdx.x] = (size_t)(tstart[v >> 16] * BM2 + (int)(v & 0xFFFFu)) * IN_F;
    }
    __syncthreads();
    const int c = threadIdx.x * 8;
    f16x8 v0 = *(const f16x8*)(yp + rbase[0] + c);
    f16x8 v1 = *(const f16x8*)(yp + rbase[1] + c);
    f16x8 v2 = *(const f16x8*)(yp + rbase[2] + c);
    f16x8 v3 = *(const f16x8*)(yp + rbase[3] + c);
    float out[8];
    #pragma unroll
    for (int j = 0; j < 8; ++j)
        out[j] = (float)v0[j] + (float)v1[j] + (float)v2[j] + (float)v3[j];
    float4* yo = (float4*)(y + (size_t)tok * IN_F + c);
    yo[0] = make_float4(out[0], out[1], out[2], out[3]);
    yo[1] = make_float4(out[4], out[5], out[6], out[7]);
}

extern "C" void kernel_launch(void* const* d_in, const int* in_sizes, int n_in,
                              void* d_out, int out_size, void* d_ws, size_t ws_size,
                              hipStream_t stream) {
    const float* x  = (const float*)d_in[0];
    const float* Wr = (const float*)d_in[1];
    const float* br = (const float*)d_in[2];
    const float* W1 = (const float*)d_in[3];
    const float* W2 = (const float*)d_in[4];
    float* y = (float*)d_out;
    char* ws = (char*)d_ws;
    int* counts = (int*)(ws + WS_COUNTS);
    int* tstart = (int*)(ws + WS_TSTART);
    unsigned short* sel = (unsigned short*)(ws + WS_SEL);
    unsigned* inv = (unsigned*)(ws + WS_INV);
    int* lists  = (int*)(ws + WS_LISTS);
    unsigned short* x_bf  = (unsigned short*)(ws + WS_XBF);
    unsigned short* w1_bf = (unsigned short*)(ws + WS_W1BF);
    unsigned short* w2_bf = (unsigned short*)(ws + WS_W2BF);
    unsigned short* h     = (unsigned short*)(ws + WS_H);
    _Float16* yp          = (_Float16*)(ws + WS_YP);

    hipLaunchKernelGGL(router_kernel, dim3(N_TOK / 8), dim3(512), 0, stream, x, Wr, br, sel, x_bf);
    hipLaunchKernelGGL(build_lists_kernel, dim3(NB), dim3(256), 0, stream, sel, counts, lists, inv);
    hipLaunchKernelGGL(scan_kernel, dim3(1), dim3(64), 0, stream, counts, tstart);
    hipLaunchKernelGGL(convert_swz_kernel, dim3(2048), dim3(256), 0, stream, W1, w1_bf, 8, 1, 3);
    hipLaunchKernelGGL(fc1_kernel, dim3(4 * MAX_MT2), dim3(512), 0, stream, x_bf, w1_bf, lists, counts, tstart, h);
    hipLaunchKernelGGL(convert_swz_kernel, dim3(2048), dim3(256), 0, stream, W2, w2_bf, 10, 0, 7);
    hipLaunchKernelGGL(fc2_kernel, dim3(8 * MAX_MT2), dim3(512), 0, stream, h, w2_bf, counts, tstart, yp);
    hipLaunchKernelGGL(reduce_kernel, dim3(N_TOK), dim3(256), 0, stream, yp, inv, tstart, y);
}

// Round 23
// 376.136 us; speedup vs baseline: 1.0606x; 1.0441x over previous
//
#include <hip/hip_runtime.h>
#include <hip/hip_bf16.h>

#define N_TOK 8192
#define IN_F  2048
#define OUT_F 8192
#define NB    16
#define BS    512
#define BM2   256
#define MAX_MT2 144         // worst-case 256-row M-tiles: 32768/256 + 16

typedef short          bf16x8  __attribute__((ext_vector_type(8)));
typedef unsigned short ushort8 __attribute__((ext_vector_type(8)));
typedef float          f32x4   __attribute__((ext_vector_type(4)));
typedef _Float16       f16x8   __attribute__((ext_vector_type(8)));

// ws layout (peak ~223 MB)
#define WS_COUNTS 0
#define WS_TSTART 64
#define WS_SEL    256                           // 8192 u16
#define WS_INV    (32*1024)                     // 8192*4 u32
#define WS_LISTS  (192*1024)                    // 16*8192 int
#define WS_XBF    (1ull<<20)                    // x_bf 32MB swizzled-by-(tok&3) (w2_bf aliases after fc1)
#define WS_W2BF   WS_XBF
#define WS_H      (WS_XBF + 33554432ull)        // h: 36864*512*2 = 36MB
#define WS_W1BF   (WS_H + 37748736ull)          // w1_bf 32MB swizzled-by-((row>>1)&3) (dead after fc1)
#define WS_YP     WS_W1BF                       // yp: 36864*2048*2 = 144MB, overlays w1_bf

static __device__ __forceinline__ unsigned short f2bf(float f) {
    __hip_bfloat16 h = __float2bfloat16(f);
    return *reinterpret_cast<unsigned short*>(&h);
}

static __device__ __forceinline__ void gload16(const unsigned short* g, unsigned short* lds) {
    __builtin_amdgcn_global_load_lds(
        (const __attribute__((address_space(1))) unsigned int*)g,
        (__attribute__((address_space(3))) unsigned int*)lds, 16, 0, 0);
}

// ---------------- router: 8 tokens/block, fp64 logits, top-4; emits x_bf (swizzled by tok&3) ----------------
__global__ __launch_bounds__(512) void router_kernel(
    const float* __restrict__ x, const float* __restrict__ Wr,
    const float* __restrict__ br, unsigned short* __restrict__ sel,
    unsigned short* __restrict__ x_bf)
{
    __shared__ float xs[8][IN_F];
    __shared__ double logits[8][NB];
    const int tid = threadIdx.x;
    const int lt = tid & 63;
    const int wv = tid >> 6;
    const int tok = blockIdx.x * 8 + wv;
    float4* xl = (float4*)xs[wv];
    const float4* xp = (const float4*)(x + (size_t)tok * IN_F);
    #pragma unroll
    for (int i = 0; i < 8; ++i) xl[lt + i * 64] = xp[lt + i * 64];
    __syncthreads();
    const int e = lt >> 2, p = lt & 3;
    const float4* wp = (const float4*)(Wr + (size_t)e * IN_F);
    double s = 0.0;
    for (int j = p; j < IN_F / 4; j += 4) {
        float4 a = xl[j], w = wp[j];
        s += (double)a.x * w.x + (double)a.y * w.y + (double)a.z * w.z + (double)a.w * w.w;
    }
    s += __shfl_down(s, 2);
    s += __shfl_down(s, 1);
    if (p == 0) logits[wv][e] = s + (double)br[e];
    __syncthreads();
    if (lt == 0) {
        unsigned used = 0, packed = 0;
        #pragma unroll
        for (int kk = 0; kk < 4; ++kk) {
            int best = 0; double bv = -1.0e300;
            #pragma unroll
            for (int i = 0; i < NB; ++i)
                if (!((used >> i) & 1u) && logits[wv][i] > bv) { bv = logits[wv][i]; best = i; }
            used |= 1u << best;
            packed |= (unsigned)best << (4 * kk);
        }
        sel[tok] = (unsigned short)packed;
    }
    const int t3 = tok & 3;
    unsigned short* drow = x_bf + (size_t)tok * IN_F;
    #pragma unroll
    for (int i = 0; i < 4; ++i) {
        const int slot = lt + i * 64;
        const float* sp = &xs[wv][slot * 8];
        ushort8 o;
        #pragma unroll
        for (int j = 0; j < 8; ++j) o[j] = f2bf(sp[j]);
        *(ushort8*)(drow + ((slot ^ t3) << 3)) = o;
    }
}

// ---------------- build per-expert token lists + inverse map (deterministic) ----------------
__global__ __launch_bounds__(256) void build_lists_kernel(
    const unsigned short* __restrict__ sel, int* __restrict__ counts,
    int* __restrict__ lists, unsigned* __restrict__ inv)
{
    const int e = blockIdx.x;
    const int t = threadIdx.x;
    unsigned short mysel[N_TOK / 256];
    int cnt = 0;
    #pragma unroll
    for (int i = 0; i < N_TOK / 256; ++i) {
        unsigned s = sel[i * 256 + t];
        mysel[i] = (unsigned short)s;
        bool m = ((s & 15u) == (unsigned)e) | (((s >> 4) & 15u) == (unsigned)e) |
                 (((s >> 8) & 15u) == (unsigned)e) | (((s >> 12) & 15u) == (unsigned)e);
        cnt += m ? 1 : 0;
    }
    __shared__ int ps[256];
    ps[t] = cnt;
    __syncthreads();
    #pragma unroll
    for (int off = 1; off < 256; off <<= 1) {
        int v = (t >= off) ? ps[t - off] : 0;
        __syncthreads();
        ps[t] += v;
        __syncthreads();
    }
    int pos = ps[t] - cnt;
    if (t == 255) counts[e] = ps[255];
    #pragma unroll
    for (int i = 0; i < N_TOK / 256; ++i) {
        unsigned s = mysel[i];
        bool m = ((s & 15u) == (unsigned)e) | (((s >> 4) & 15u) == (unsigned)e) |
                 (((s >> 8) & 15u) == (unsigned)e) | (((s >> 12) & 15u) == (unsigned)e);
        if (m) {
            const int tok = i * 256 + t;
            int j = ((s & 15u) == (unsigned)e) ? 0 :
                    (((s >> 4) & 15u) == (unsigned)e) ? 1 :
                    (((s >> 8) & 15u) == (unsigned)e) ? 2 : 3;
            inv[tok * 4 + j] = ((unsigned)e << 16) | (unsigned)pos;
            lists[e * N_TOK + pos++] = tok;
        }
    }
}

__global__ void scan_kernel(const int* __restrict__ counts, int* __restrict__ tstart)
{
    if (threadIdx.x == 0) {
        int acc = 0;
        for (int i = 0; i < NB; ++i) { tstart[i] = acc; acc += (counts[i] + BM2 - 1) / BM2; }
        tstart[NB] = acc;
    }
}

// ---------------- W convert: fp32 -> bf16, slot-XOR key = (row >> rsh) & mask ----------------
__global__ __launch_bounds__(256) void convert_swz_kernel(
    const float* __restrict__ src, unsigned short* __restrict__ dst, int sh, int rsh, int mask)
{
    const int total = 1 << 21;
    for (int id = blockIdx.x * 256 + threadIdx.x; id < total; id += 2048 * 256) {
        const int row = id >> sh;
        const int sr  = id & ((1 << sh) - 1);
        const int ps  = sr ^ ((row >> rsh) & mask);
        const float4* s4 = (const float4*)(src + ((size_t)id << 3));
        float4 p0 = s4[0], p1 = s4[1];
        ushort8 o;
        o[0] = f2bf(p0.x); o[1] = f2bf(p0.y); o[2] = f2bf(p0.z); o[3] = f2bf(p0.w);
        o[4] = f2bf(p1.x); o[5] = f2bf(p1.y); o[6] = f2bf(p1.z); o[7] = f2bf(p1.w);
        *(ushort8*)(dst + (((size_t)(row) << sh) << 3) + ((size_t)ps << 3)) = o;
    }
}

// ======== fc1: 128x128 tile (halves of 256-row blocks), BK=32, 8 waves, 3-buffer 48KB -> 3 blocks/CU ========
// Same counted-vmcnt ledger (issue k+2's 2 loads, vmcnt(2), tail drain); same (r>>1)&3 swizzle family.
__global__ __launch_bounds__(512, 6) void fc1_kernel(
    const unsigned short* __restrict__ x_bf, const unsigned short* __restrict__ w1_bf,
    const int* __restrict__ lists, const int* __restrict__ counts,
    const int* __restrict__ tstart, unsigned short* __restrict__ h)
{
    __shared__ unsigned short lds[3 * 8192];   // per buf: A 8KB + B 8KB = 16KB
    const int bid = blockIdx.x;
    const int newid = (bid & 7) * 144 + (bid >> 3);   // bijective: 1152 = 8*144
    const int nt = newid & 3;                         // W1 col-tile (128 wide)
    const int mts = newid >> 2;                       // 0..287 half-tiles
    const int mt = mts >> 1, half = mts & 1;          // 256-row block + which half
    if (mt >= tstart[NB]) return;
    int b = 0;
    #pragma unroll
    for (int i = 1; i < NB; ++i) b += (mt >= tstart[i]);
    const int cnt  = counts[b];
    const int row0 = (mt - tstart[b]) * BM2 + half * 128;   // expert-relative base of this 128-row tile
    const int tid  = threadIdx.x;
    const int wave = tid >> 6, lane = tid & 63;
    const int sl = tid & 3;              // staging 16B-slot within 64B window
    const int srw = tid >> 2;            // staging row 0..127
    const int skey = (srw >> 1) & 3;

    const unsigned short* aS0;
    const unsigned short* bS0;
    {
        int gr = min(row0 + srw, cnt - 1);
        gr = max(gr, 0);
        int tok = lists[b * N_TOK + gr];
        aS0 = x_bf + (size_t)tok * IN_F + ((sl ^ skey ^ (tok & 3)) << 3);
        bS0 = w1_bf + (size_t)(b * BS + nt * 128 + srw) * IN_F + (sl << 3);   // store-key == read-key -> linear
    }

    const int lr16 = lane & 15, q = lane >> 4;
    const int wm = (wave >> 2) * 64, wn = (wave & 3) * 32;   // wave tile 64x32
    int offA[4], offB[2];
    #pragma unroll
    for (int i = 0; i < 4; ++i) { const int r = wm + i * 16 + lr16; offA[i] = r * 32 + ((q ^ ((r >> 1) & 3)) << 3); }
    #pragma unroll
    for (int j = 0; j < 2; ++j) { const int r = wn + j * 16 + lr16; offB[j] = 4096 + r * 32 + ((q ^ ((r >> 1) & 3)) << 3); }

    f32x4 acc[4][2];
    #pragma unroll
    for (int i = 0; i < 4; ++i)
        #pragma unroll
        for (int j = 0; j < 2; ++j) acc[i][j] = (f32x4)0.0f;

#define ST1(k, buf) \
    { gload16(aS0 + (size_t)(k) * 32, lds + (buf) * 8192 + tid * 8); \
      gload16(bS0 + (size_t)(k) * 32, lds + (buf) * 8192 + 4096 + tid * 8); }

    ST1(0, 0); ST1(1, 1);
    asm volatile("s_waitcnt vmcnt(2)" ::: "memory");
    __builtin_amdgcn_s_barrier();

    const int NK = IN_F / 32;   // 64
    int cur = 0;
    for (int k = 0; k < NK; ++k) {
        const unsigned short* L = lds + cur * 8192;
        const int nxt = (cur == 0) ? 2 : cur - 1;        // (cur+2)%3
        bf16x8 a[4], bb[2];
        #pragma unroll
        for (int i = 0; i < 4; ++i) a[i]  = *(const bf16x8*)&L[offA[i]];
        #pragma unroll
        for (int j = 0; j < 2; ++j) bb[j] = *(const bf16x8*)&L[offB[j]];
        if (k + 2 < NK) {
            ST1(k + 2, nxt);
            asm volatile("s_waitcnt vmcnt(2)" ::: "memory");   // tile k+1 landed; k+2 in flight
        } else if (k + 1 < NK) {
            asm volatile("s_waitcnt vmcnt(0)" ::: "memory");   // tail drain
        }
        __builtin_amdgcn_s_barrier();
        asm volatile("s_waitcnt lgkmcnt(0)" ::: "memory");
        __builtin_amdgcn_sched_barrier(0);
        __builtin_amdgcn_s_setprio(1);
        #pragma unroll
        for (int i = 0; i < 4; ++i)
            #pragma unroll
            for (int j = 0; j < 2; ++j)
                acc[i][j] = __builtin_amdgcn_mfma_f32_16x16x32_bf16(a[i], bb[j], acc[i][j], 0, 0, 0);
        __builtin_amdgcn_s_setprio(0);
        __builtin_amdgcn_sched_barrier(0);
        __builtin_amdgcn_s_barrier();
        cur = (cur == 2) ? 0 : cur + 1;
    }
    // epilogue: exact gelu, store h pre-swizzled by global-row&7 ((half*128+lrow)&7 == lrow&7)
    #pragma unroll
    for (int i = 0; i < 4; ++i) {
        #pragma unroll
        for (int r = 0; r < 4; ++r) {
            const int lrow = wm + i * 16 + q * 4 + r;
            if (row0 + lrow < cnt) {
                const size_t hrow = (size_t)(mt * BM2 + half * 128 + lrow) * BS;
                const int r7 = (lrow & 7) << 3;
                #pragma unroll
                for (int j = 0; j < 2; ++j) {
                    const int col = nt * 128 + wn + j * 16 + lr16;
                    float v = acc[i][j][r];
                    v = 0.5f * v * (1.0f + erff(v * 0.70710678118654752f));
                    h[hrow + (col ^ r7)] = f2bf(v);
                }
            }
        }
    }
#undef ST1
}

// ======== fc2: 256x256 tile, 8 waves (2x4), 2-buffer phase-interleaved; h @ W2_b^T -> yp fp16 (R12-green) ========
__global__ __launch_bounds__(512) void fc2_kernel(
    const unsigned short* __restrict__ h, const unsigned short* __restrict__ w2_bf,
    const int* __restrict__ counts, const int* __restrict__ tstart,
    _Float16* __restrict__ yp)
{
    __shared__ unsigned short lds[2][32768];   // per buf: A 32KB + B 32KB
    const int bid = blockIdx.x;
    const int newid = (bid & 7) * 144 + (bid >> 3);  // bijective: 1152 = 8*144
    const int nt = newid & 7, mt = newid >> 3;
    if (mt >= tstart[NB]) return;
    int b = 0;
    #pragma unroll
    for (int i = 1; i < NB; ++i) b += (mt >= tstart[i]);
    const int cnt  = counts[b];
    const int row0 = (mt - tstart[b]) * BM2;
    const int tid  = threadIdx.x;
    const int wave = tid >> 6, lane = tid & 63;
    const int sph = lane & 7;
    const int rbase = wave * 8 + (lane >> 3);        // 0..63

    const unsigned short* aS[4];
    const unsigned short* bS[4];
    #pragma unroll
    for (int g = 0; g < 4; ++g) {
        const int r = g * 64 + rbase;
        aS[g] = h + (size_t)(mt * BM2 + r) * BS + (sph << 3);
        bS[g] = w2_bf + (size_t)(nt * 256 + r) * OUT_F + b * BS + (sph << 3);
    }
    const int wbase = wave * 512;

    const int lr16 = lane & 15, q = lane >> 4;
    const int wr = (wave >> 2) * 128, wc = (wave & 3) * 64;
    int offA[8], offB[4];
    #pragma unroll
    for (int i = 0; i < 8; ++i) { const int r = wr + i * 16 + lr16; offA[i] = r * 64 + ((q ^ (r & 7)) << 3); }
    #pragma unroll
    for (int j = 0; j < 4; ++j) { const int r = wc + j * 16 + lr16; offB[j] = 16384 + r * 64 + ((q ^ (r & 7)) << 3); }

    f32x4 acc[8][4];
    #pragma unroll
    for (int i = 0; i < 8; ++i)
        #pragma unroll
        for (int j = 0; j < 4; ++j) acc[i][j] = (f32x4)0.0f;

#define ST2(k, buf) \
    { _Pragma("unroll") for (int g = 0; g < 4; ++g) \
        gload16(aS[g] + (size_t)(k) * 64, &lds[buf][g * 4096 + wbase]); \
      _Pragma("unroll") for (int g = 0; g < 4; ++g) \
        gload16(bS[g] + (size_t)(k) * 64, &lds[buf][16384 + g * 4096 + wbase]); }

#define MFMA_8x4 \
    __builtin_amdgcn_s_barrier(); \
    asm volatile("s_waitcnt lgkmcnt(0)" ::: "memory"); \
    __builtin_amdgcn_sched_barrier(0); \
    __builtin_amdgcn_s_setprio(1); \
    _Pragma("unroll") for (int i = 0; i < 8; ++i) \
        _Pragma("unroll") for (int j = 0; j < 4; ++j) \
            acc[i][j] = __builtin_amdgcn_mfma_f32_16x16x32_bf16(a[i], bb[j], acc[i][j], 0, 0, 0); \
    __builtin_amdgcn_s_setprio(0); \
    __builtin_amdgcn_sched_barrier(0); \
    __builtin_amdgcn_s_barrier();

    ST2(0, 0);
    asm volatile("s_waitcnt vmcnt(0)" ::: "memory");
    __builtin_amdgcn_s_barrier();

    const int NK = BS / 64;   // 8
    for (int k = 0; k < NK; ++k) {
        const int cur = k & 1;
        const unsigned short* L = lds[cur];
        // phase A: ds_read half0, issue ALL of tile k+1's staging
        {
            bf16x8 a[8], bb[4];
            #pragma unroll
            for (int i = 0; i < 8; ++i) a[i]  = *(const bf16x8*)&L[offA[i]];
            #pragma unroll
            for (int j = 0; j < 4; ++j) bb[j] = *(const bf16x8*)&L[offB[j]];
            if (k + 1 < NK) ST2(k + 1, cur ^ 1);
            MFMA_8x4
        }
        // phase B: ds_read half1; drain staging BEFORE the barrier (race-safe)
        {
            bf16x8 a[8], bb[4];
            #pragma unroll
            for (int i = 0; i < 8; ++i) a[i]  = *(const bf16x8*)&L[offA[i] ^ 32];
            #pragma unroll
            for (int j = 0; j < 4; ++j) bb[j] = *(const bf16x8*)&L[offB[j] ^ 32];
            if (k + 1 < NK) asm volatile("s_waitcnt vmcnt(0)" ::: "memory");
            MFMA_8x4
        }
    }
    // epilogue: store fp16 partials
    #pragma unroll
    for (int i = 0; i < 8; ++i) {
        #pragma unroll
        for (int r = 0; r < 4; ++r) {
            const int lrow = wr + i * 16 + q * 4 + r;
            if (row0 + lrow < cnt) {
                _Float16* yrow = yp + (size_t)(mt * BM2 + lrow) * IN_F + nt * 256 + wc + lr16;
                #pragma unroll
                for (int j = 0; j < 4; ++j)
                    yrow[j * 16] = (_Float16)acc[i][j][r];
            }
        }
    }
#undef ST2
#undef MFMA_8x4
}

// ---------------- reduce: y[t] = sum of the token's 4 fp16 partial rows ----------------
__global__ __launch_bounds__(256) void reduce_kernel(
    const _Float16* __restrict__ yp, const unsigned* __restrict__ inv,
    const int* __restrict__ tstart, float* __restrict__ y)
{
    const int tok = blockIdx.x;
    __shared__ size_t rbase[4];
    if (threadIdx.x < 4) {
        unsigned v = inv[tok * 4 + threadIdx.x];
        rbase[threadIdx.x] = (size_t)(tstart[v >> 16] * BM2 + (int)(v & 0xFFFFu)) * IN_F;
    }
    __syncthreads();
    const int c = threadIdx.x * 8;
    f16x8 v0 = *(const f16x8*)(yp + rbase[0] + c);
    f16x8 v1 = *(const f16x8*)(yp + rbase[1] + c);
    f16x8 v2 = *(const f16x8*)(yp + rbase[2] + c);
    f16x8 v3 = *(const f16x8*)(yp + rbase[3] + c);
    float out[8];
    #pragma unroll
    for (int j = 0; j < 8; ++j)
        out[j] = (float)v0[j] + (float)v1[j] + (float)v2[j] + (float)v3[j];
    float4* yo = (float4*)(y + (size_t)tok * IN_F + c);
    yo[0] = make_float4(out[0], out[1], out[2], out[3]);
    yo[1] = make_float4(out[4], out[5], out[6], out[7]);
}

extern "C" void kernel_launch(void* const* d_in, const int* in_sizes, int n_in,
                              void* d_out, int out_size, void* d_ws, size_t ws_size,
                              hipStream_t stream) {
    const float* x  = (const float*)d_in[0];
    const float* Wr = (const float*)d_in[1];
    const float* br = (const float*)d_in[2];
    const float* W1 = (const float*)d_in[3];
    const float* W2 = (const float*)d_in[4];
    float* y = (float*)d_out;
    char* ws = (char*)d_ws;
    int* counts = (int*)(ws + WS_COUNTS);
    int* tstart = (int*)(ws + WS_TSTART);
    unsigned short* sel = (unsigned short*)(ws + WS_SEL);
    unsigned* inv = (unsigned*)(ws + WS_INV);
    int* lists  = (int*)(ws + WS_LISTS);
    unsigned short* x_bf  = (unsigned short*)(ws + WS_XBF);
    unsigned short* w1_bf = (unsigned short*)(ws + WS_W1BF);
    unsigned short* w2_bf = (unsigned short*)(ws + WS_W2BF);
    unsigned short* h     = (unsigned short*)(ws + WS_H);
    _Float16* yp          = (_Float16*)(ws + WS_YP);

    hipLaunchKernelGGL(router_kernel, dim3(N_TOK / 8), dim3(512), 0, stream, x, Wr, br, sel, x_bf);
    hipLaunchKernelGGL(build_lists_kernel, dim3(NB), dim3(256), 0, stream, sel, counts, lists, inv);
    hipLaunchKernelGGL(scan_kernel, dim3(1), dim3(64), 0, stream, counts, tstart);
    hipLaunchKernelGGL(convert_swz_kernel, dim3(2048), dim3(256), 0, stream, W1, w1_bf, 8, 1, 3);
    hipLaunchKernelGGL(fc1_kernel, dim3(8 * MAX_MT2), dim3(512), 0, stream, x_bf, w1_bf, lists, counts, tstart, h);
    hipLaunchKernelGGL(convert_swz_kernel, dim3(2048), dim3(256), 0, stream, W2, w2_bf, 10, 0, 7);
    hipLaunchKernelGGL(fc2_kernel, dim3(8 * MAX_MT2), dim3(512), 0, stream, h, w2_bf, counts, tstart, yp);
    hipLaunchKernelGGL(reduce_kernel, dim3(N_TOK), dim3(256), 0, stream, yp, inv, tstart, y);
}